// Round 8
// baseline (137.762 us; speedup 1.0000x reference)
//
#include <hip/hip_runtime.h>

// PPO model loss — wave-autonomous GAE, zero hot-path atomics, rescan-only.
// R8: K2 compose de-latencied — coeffs stored [row][seg] so each row-thread
// loads all 8 segments upfront as float4 pairs (no dependent-load chain),
// then pure ALU. K3 block = 256 (2048 blocks) for finer scheduling tails.
// Two-pass structure is forced: vf/pg are piecewise (max of quadratics) in
// the segment carry, so no closed-form fold into K1.
//
// ws layout:
//   [0)    2 floats: meanf, invstdf (written by K2)
//   [64)   7 coeff arrays of NS floats, [row][seg] (wsL,wsM,b0,b1,q0,q1,q2)
//          + wsC (NS floats, [row][seg] = segment-id order)
//   then   3*nblk3 doubles: per-block (vf,pg,n) partials

static constexpr int T_DIM = 4096;
static constexpr int SEG   = 512;           // elements per segment (one wave)
static constexpr int NSEG  = T_DIM / SEG;   // 8 segments per row
static constexpr int CH    = 8;             // elements per lane
static constexpr int BT1   = 256;           // K1 block
static constexpr int NW1   = BT1 / 64;
static constexpr int BT3   = 256;           // K3 block
static constexpr int NW3   = BT3 / 64;      // 4

#define CDEC 0.95f
#define CLIPR 0.2f
#define CLIPV 0.2f

__device__ __forceinline__ double wave_sum_d(double v) {
#pragma unroll
  for (int d = 32; d > 0; d >>= 1) v += __shfl_down(v, d);
  return v;
}
__device__ __forceinline__ float wave_sum_f(float v) {
#pragma unroll
  for (int d = 32; d > 0; d >>= 1) v += __shfl_down(v, d);
  return v;
}
// inclusive suffix scan of affine (L, M) across the 64-lane wave
__device__ __forceinline__ void wave_suffix(float& sL, float& sM, int lane) {
#pragma unroll
  for (int d = 1; d < 64; d <<= 1) {
    float oL = __shfl_down(sL, d);
    float oM = __shfl_down(sM, d);
    if (lane + d < 64) { sL += sM * oL; sM *= oM; }
  }
}

// ---------------- K1: per-segment affine + stats coefficients --------------
__global__ __launch_bounds__(BT1) void seg_stats_kernel(
    const float* __restrict__ old_values,
    const float* __restrict__ rewards,
    float* __restrict__ wsL, float* __restrict__ wsM,
    float* __restrict__ wsB0, float* __restrict__ wsB1,
    float* __restrict__ wsQ0, float* __restrict__ wsQ1,
    float* __restrict__ wsQ2) {
  const int tid  = threadIdx.x;
  const int lane = tid & 63;
  const int gw   = blockIdx.x * NW1 + (tid >> 6);  // segment id = row*NSEG+seg
  const int seg  = gw & (NSEG - 1);
  const float c  = CDEC;
  const long base = (long)gw * SEG + (long)lane * CH;

  const float4 rv0 = *(const float4*)(rewards + base);
  const float4 rv1 = *(const float4*)(rewards + base + 4);
  const float4 vv0 = *(const float4*)(old_values + base);
  const float4 vv1 = *(const float4*)(old_values + base + 4);

  float v[CH + 1], rw[CH];
  v[0] = vv0.x; v[1] = vv0.y; v[2] = vv0.z; v[3] = vv0.w;
  v[4] = vv1.x; v[5] = vv1.y; v[6] = vv1.z; v[7] = vv1.w;
  rw[0] = rv0.x; rw[1] = rv0.y; rw[2] = rv0.z; rw[3] = rv0.w;
  rw[4] = rv1.x; rw[5] = rv1.y; rw[6] = rv1.z; rw[7] = rv1.w;
  float nv = __shfl_down(v[0], 1);
  if (lane == 63) nv = (seg == NSEG - 1) ? 0.f : old_values[base + CH];
  v[CH] = nv;

  float Qc = 0.f, Q2 = 0.f, cCH;
  {
    float pw = 1.f;
#pragma unroll
    for (int i = 0; i < CH; ++i) { pw *= c; Qc += pw; Q2 += pw * pw; }
    cCH = pw;
  }

  // local suffix scan (zero carry-in)
  float L[CH];
  L[CH - 1] = rw[CH - 1] + v[CH] - v[CH - 1];
#pragma unroll
  for (int j = CH - 2; j >= 0; --j)
    L[j] = (rw[j] + v[j + 1] - v[j]) + c * L[j + 1];

  float P = 0.f, P2 = 0.f, cross = 0.f;
  {
    float pw = 1.f;
#pragma unroll
    for (int j = CH - 1; j >= 0; --j) {
      pw *= c;                                  // c^(CH-j)
      P += L[j]; P2 += L[j] * L[j]; cross += L[j] * pw;
    }
  }

  float sL = L[0], sM = cCH;
  wave_suffix(sL, sM, lane);
  float nLc = __shfl_down(sL, 1);
  float nMc = __shfl_down(sM, 1);
  if (lane == 63) { nLc = 0.f; nMc = 1.f; }

  // stats as polynomials in segment carry C (thread carry = nLc + nMc*C)
  float b0 = P + Qc * nLc;
  float b1 = Qc * nMc;
  float q0 = P2 + 2.f * nLc * cross + Q2 * nLc * nLc;
  float q1 = 2.f * nMc * cross + 2.f * Q2 * nLc * nMc;
  float q2 = Q2 * nMc * nMc;

  b0 = wave_sum_f(b0); b1 = wave_sum_f(b1);
  q0 = wave_sum_f(q0); q1 = wave_sum_f(q1); q2 = wave_sum_f(q2);

  if (lane == 0) {
    wsL[gw] = sL;  wsM[gw] = sM;       // [row][seg] natural order
    wsB0[gw] = b0; wsB1[gw] = b1;
    wsQ0[gw] = q0; wsQ1[gw] = q1; wsQ2[gw] = q2;
  }
}

// ---------------- K2: single-block compose + whitening constants -----------
// [row][seg] layout: each thread (one row) loads its 8 segments as 2 float4s
// per coeff array UPFRONT, then pure-ALU serial compose. No dependent loads.
__global__ __launch_bounds__(1024) void compose_kernel(
    const float* __restrict__ wsL, const float* __restrict__ wsM,
    const float* __restrict__ wsB0, const float* __restrict__ wsB1,
    const float* __restrict__ wsQ0, const float* __restrict__ wsQ1,
    const float* __restrict__ wsQ2,
    float* __restrict__ wsC, float* __restrict__ scal,
    int nrows, long Ntot) {
  const int tid  = threadIdx.x;
  const int lane = tid & 63;
  const int wave = tid >> 6;

  double s1 = 0.0, s2 = 0.0;
  if (tid < nrows) {
    const long i0 = (long)tid * NSEG;
    float Lr[NSEG], Mr[NSEG], B0[NSEG], B1[NSEG], Q0[NSEG], Q1[NSEG], Q2[NSEG];
#define LD8(dst, src)                                                          \
    { const float4 a_ = *(const float4*)(src + i0);                            \
      const float4 b_ = *(const float4*)(src + i0 + 4);                        \
      dst[0]=a_.x; dst[1]=a_.y; dst[2]=a_.z; dst[3]=a_.w;                      \
      dst[4]=b_.x; dst[5]=b_.y; dst[6]=b_.z; dst[7]=b_.w; }
    LD8(Lr, wsL) LD8(Mr, wsM) LD8(B0, wsB0) LD8(B1, wsB1)
    LD8(Q0, wsQ0) LD8(Q1, wsQ1) LD8(Q2, wsQ2)
#undef LD8
    float Cv[NSEG];
    float C = 0.f;
#pragma unroll
    for (int s = NSEG - 1; s >= 0; --s) {
      Cv[s] = C;
      s1 += (double)(B0[s] + B1[s] * C);
      s2 += (double)(Q0[s] + (Q1[s] + Q2[s] * C) * C);
      C = Lr[s] + Mr[s] * C;
    }
    *(float4*)(wsC + i0)     = make_float4(Cv[0], Cv[1], Cv[2], Cv[3]);
    *(float4*)(wsC + i0 + 4) = make_float4(Cv[4], Cv[5], Cv[6], Cv[7]);
  }

  __shared__ double red[2][16];
  double r1 = wave_sum_d(s1);
  double r2 = wave_sum_d(s2);
  if (lane == 0) { red[0][wave] = r1; red[1][wave] = r2; }
  __syncthreads();
  if (tid == 0) {
    double S1 = 0.0, S2 = 0.0;
#pragma unroll
    for (int w = 0; w < 16; ++w) { S1 += red[0][w]; S2 += red[1][w]; }
    const double mean = S1 / (double)Ntot;
    const double var  = (S2 - S1 * S1 / (double)Ntot) / (double)(Ntot - 1);
    scal[0] = (float)mean;
    scal[1] = (float)(1.0 / sqrt(var + 1e-8));
  }
}

// ---------------- K3: loss (rescan, per-block partials) --------------------
__global__ __launch_bounds__(BT3) void loss_kernel(
    const float* __restrict__ logprobs,
    const float* __restrict__ values,
    const float* __restrict__ old_logprobs,
    const float* __restrict__ old_values,
    const float* __restrict__ rewards,
    const int*   __restrict__ mask,
    const float* __restrict__ wsC, const float* __restrict__ scal,
    double* __restrict__ part) {
  const int tid  = threadIdx.x;
  const int lane = tid & 63;
  const int wave = tid >> 6;
  const int gw   = blockIdx.x * NW3 + wave;
  const int seg  = gw & (NSEG - 1);
  const float c  = CDEC;
  const long base = (long)gw * SEG + (long)lane * CH;

  const float meanf = scal[0], invstdf = scal[1];

  const float4 rv0 = *(const float4*)(rewards + base);
  const float4 rv1 = *(const float4*)(rewards + base + 4);
  const float4 vv0 = *(const float4*)(old_values + base);
  const float4 vv1 = *(const float4*)(old_values + base + 4);
  const float4 va0 = *(const float4*)(values + base);
  const float4 va1 = *(const float4*)(values + base + 4);
  const float4 lp0 = *(const float4*)(logprobs + base);
  const float4 lp1 = *(const float4*)(logprobs + base + 4);
  const float4 ol0 = *(const float4*)(old_logprobs + base);
  const float4 ol1 = *(const float4*)(old_logprobs + base + 4);
  const int4  mk0  = *(const int4*)(mask + base);
  const int4  mk1  = *(const int4*)(mask + base + 4);

  float v[CH + 1], rw[CH], va[CH], lp[CH], ol[CH];
  int mk[CH];
  v[0] = vv0.x; v[1] = vv0.y; v[2] = vv0.z; v[3] = vv0.w;
  v[4] = vv1.x; v[5] = vv1.y; v[6] = vv1.z; v[7] = vv1.w;
  rw[0] = rv0.x; rw[1] = rv0.y; rw[2] = rv0.z; rw[3] = rv0.w;
  rw[4] = rv1.x; rw[5] = rv1.y; rw[6] = rv1.z; rw[7] = rv1.w;
  va[0] = va0.x; va[1] = va0.y; va[2] = va0.z; va[3] = va0.w;
  va[4] = va1.x; va[5] = va1.y; va[6] = va1.z; va[7] = va1.w;
  lp[0] = lp0.x; lp[1] = lp0.y; lp[2] = lp0.z; lp[3] = lp0.w;
  lp[4] = lp1.x; lp[5] = lp1.y; lp[6] = lp1.z; lp[7] = lp1.w;
  ol[0] = ol0.x; ol[1] = ol0.y; ol[2] = ol0.z; ol[3] = ol0.w;
  ol[4] = ol1.x; ol[5] = ol1.y; ol[6] = ol1.z; ol[7] = ol1.w;
  mk[0] = mk0.x; mk[1] = mk0.y; mk[2] = mk0.z; mk[3] = mk0.w;
  mk[4] = mk1.x; mk[5] = mk1.y; mk[6] = mk1.z; mk[7] = mk1.w;

  float nv = __shfl_down(v[0], 1);
  if (lane == 63) nv = (seg == NSEG - 1) ? 0.f : old_values[base + CH];
  v[CH] = nv;

  float cCH;
  { float pw = 1.f;
#pragma unroll
    for (int i = 0; i < CH; ++i) pw *= c;
    cCH = pw; }

  float L[CH];
  L[CH - 1] = rw[CH - 1] + v[CH] - v[CH - 1];
#pragma unroll
  for (int j = CH - 2; j >= 0; --j)
    L[j] = (rw[j] + v[j + 1] - v[j]) + c * L[j + 1];

  float sL = L[0], sM = cCH;
  wave_suffix(sL, sM, lane);
  float nLc = __shfl_down(sL, 1);
  float nMc = __shfl_down(sM, 1);
  if (lane == 63) { nLc = 0.f; nMc = 1.f; }
  const float carry = nLc + nMc * wsC[gw];

  float vf_s = 0.f, pg_s = 0.f, n_s = 0.f;
  {
    float cpw = 1.f;
#pragma unroll
    for (int j = CH - 1; j >= 0; --j) {
      cpw *= c;                       // c^(CH-j)
      const float A   = L[j] + carry * cpw;
      const float mf  = (float)mk[j];
      const float ret = A + v[j];
      const float vc2 = fminf(fmaxf(va[j], v[j] - CLIPV), v[j] + CLIPV);
      const float d1  = va[j] - ret, d2 = vc2 - ret;
      vf_s += fmaxf(d1 * d1, d2 * d2) * mf;
      const float ratio = expf((lp[j] - ol[j]) * mf);
      const float a     = (A - meanf) * invstdf;
      const float p1    = -a * ratio;
      const float p2    = -a * fminf(fmaxf(ratio, 1.f - CLIPR), 1.f + CLIPR);
      pg_s += fmaxf(p1, p2) * mf;
      n_s  += mf;
    }
  }

  __shared__ double red[3][NW3];
  double r0 = wave_sum_d((double)vf_s);
  double r1 = wave_sum_d((double)pg_s);
  double r2 = wave_sum_d((double)n_s);
  if (lane == 0) { red[0][wave] = r0; red[1][wave] = r1; red[2][wave] = r2; }
  __syncthreads();
  if (tid == 0) {
    double t0 = 0.0, t1 = 0.0, t2 = 0.0;
#pragma unroll
    for (int w = 0; w < NW3; ++w) {
      t0 += red[0][w]; t1 += red[1][w]; t2 += red[2][w];
    }
    part[3 * blockIdx.x + 0] = t0;
    part[3 * blockIdx.x + 1] = t1;
    part[3 * blockIdx.x + 2] = t2;
  }
}

// ---------------- K4: finalize (reduce per-block partials) -----------------
__global__ __launch_bounds__(1024) void finalize_kernel(
    const double* __restrict__ part, int nblk, float* __restrict__ out) {
  const int tid  = threadIdx.x;
  const int lane = tid & 63;
  const int wave = tid >> 6;
  double vf = 0.0, pg = 0.0, n = 0.0;
  for (int i = tid; i < nblk; i += 1024) {
    vf += part[3 * i + 0];
    pg += part[3 * i + 1];
    n  += part[3 * i + 2];
  }
  __shared__ double red[3][16];
  vf = wave_sum_d(vf); pg = wave_sum_d(pg); n = wave_sum_d(n);
  if (lane == 0) { red[0][wave] = vf; red[1][wave] = pg; red[2][wave] = n; }
  __syncthreads();
  if (tid == 0) {
    double t0 = 0.0, t1 = 0.0, t2 = 0.0;
#pragma unroll
    for (int w = 0; w < 16; ++w) {
      t0 += red[0][w]; t1 += red[1][w]; t2 += red[2][w];
    }
    out[0] = (float)(t1 / t2 + 0.5 * t0 / t2);   // VF_COEF = 1.0
  }
}

extern "C" void kernel_launch(void* const* d_in, const int* in_sizes, int n_in,
                              void* d_out, int out_size, void* d_ws, size_t ws_size,
                              hipStream_t stream) {
  const float* logprobs     = (const float*)d_in[0];
  const float* values       = (const float*)d_in[1];
  const float* old_logprobs = (const float*)d_in[2];
  const float* old_values   = (const float*)d_in[3];
  const float* rewards      = (const float*)d_in[4];
  const int*   mask         = (const int*)d_in[5];

  const long total = (long)in_sizes[0];
  const int  nrows = (int)(total / T_DIM);
  const int  NS    = nrows * NSEG;

  char* p = (char*)d_ws;
  float* scal = (float*)p;                         // 2 floats
  float* f    = (float*)(p + 64);
  float *wsL = f, *wsM = f + NS, *wsB0 = f + 2L * NS, *wsB1 = f + 3L * NS,
        *wsQ0 = f + 4L * NS, *wsQ1 = f + 5L * NS, *wsQ2 = f + 6L * NS,
        *wsC = f + 7L * NS;
  const size_t off_part = 64 + (size_t)8 * NS * 4;
  double* part = (double*)(p + off_part);

  const int nblk1 = NS / NW1;
  const int nblk3 = NS / NW3;

  seg_stats_kernel<<<nblk1, BT1, 0, stream>>>(old_values, rewards, wsL, wsM,
                                              wsB0, wsB1, wsQ0, wsQ1, wsQ2);
  compose_kernel<<<1, 1024, 0, stream>>>(wsL, wsM, wsB0, wsB1, wsQ0, wsQ1,
                                         wsQ2, wsC, scal, nrows, total);
  loss_kernel<<<nblk3, BT3, 0, stream>>>(logprobs, values, old_logprobs,
                                         old_values, rewards, mask, wsC, scal,
                                         part);
  finalize_kernel<<<1, 1024, 0, stream>>>(part, nblk3, (float*)d_out);
}